// Round 1
// 414.821 us; speedup vs baseline: 1.0757x; 1.0757x over previous
//
#include <hip/hip_runtime.h>
#include <math.h>

typedef __attribute__((ext_vector_type(8))) short short8;
typedef __attribute__((ext_vector_type(4))) float float4v;

// round-half-up f32->bf16 (max 0.5 ulp, ties up): 2 instrs
__device__ __forceinline__ short f2bf(float f) {
    return (short)((__float_as_uint(f) + 0x8000u) >> 16);
}
// sigmoid-approx gelu: x * sigmoid(1.702x); 1.702*log2(e) = 2.4554542
__device__ __forceinline__ float gelu_sig(float x) {
    return x * __builtin_amdgcn_rcpf(1.f + __builtin_amdgcn_exp2f(-2.4554542f * x));
}
__device__ __forceinline__ void stage16(const short* g, short* l) {
    __builtin_amdgcn_global_load_lds(
        (__attribute__((address_space(1))) void*)g,
        (__attribute__((address_space(3))) void*)l, 16, 0, 0);
}

// ---------------- weight conversion: fp32 -> bf16 in B-fragment order ----------------
// B-frag (mfma 16x16x32 bf16): lane l holds B[k = kc*32 + (l>>4)*8 + j][n = tile*16 + (l&15)]
// ws (shorts): [0,27648) qkv_w  [(tile 0..17)*3+kc]
//              [27648,64512) w1 [(t*6+tn)*3+kc]            (t-slice = 9216 contiguous)
//              [64512,101376) w2 [(t*6+tn)*3+kc], k-rows t*96+kc*32.. (t-slice contiguous)
__global__ void convert_weights(const float* __restrict__ qkv_w,
                                const float* __restrict__ w1,
                                const float* __restrict__ w2,
                                short* __restrict__ ws) {
    int e = blockIdx.x * 256 + threadIdx.x;
    if (e >= 101376) return;
    if (e < 27648) {
        int j = e & 7, lane = (e >> 3) & 63, fc = e >> 9;
        int kc = fc % 3, t = fc / 3;
        int k = kc * 32 + ((lane >> 4) << 3) + j;
        int col = t * 16 + (lane & 15);
        ws[e] = f2bf(qkv_w[k * 288 + col]);
    } else if (e < 64512) {
        int e2 = e - 27648;
        int j = e2 & 7, lane = (e2 >> 3) & 63, fc = e2 >> 9;
        int kc = fc % 3, tile = fc / 3;             // tile = t*6+tn
        int k = kc * 32 + ((lane >> 4) << 3) + j;
        int col = tile * 16 + (lane & 15);          // = t*96 + tn*16 + (lane&15)... col in [0,384)
        ws[27648 + e2] = f2bf(w1[k * 384 + col]);
    } else {
        int e3 = e - 64512;
        int j = e3 & 7, lane = (e3 >> 3) & 63, fc = e3 >> 9;
        int kc = fc % 3, tn = (fc / 3) % 6, t = fc / 18;
        int k = t * 96 + kc * 32 + ((lane >> 4) << 3) + j;
        int col = tn * 16 + (lane & 15);
        ws[64512 + e3] = f2bf(w2[k * 96 + col]);
    }
}

// ---------------- fused swin block ----------------
// One block per 7x7 window, 4 waves. LDS (shorts), total 19456 (38912 B -> 4 blocks/CU).
// Region lifetime overlap (all hand-offs barrier- or same-wave-ordered):
//   R0_ [0,6656)      XA: LN'd x rows (stride 104) -> [sync after af loads] K rows
//                     -> [sync after QK^T reads] O rows (bf16) -> H (MLP hidden)
//   Q_  [6656,13312)  Q rows (stride 104) -> [post-QK^T sync] P (softmax, stride 72)
//   VB_ [13312,19456) V in B-frag layout
//   WS_ [6656,15872)  weight stage in phase E (over dead P + VB; loop-top sync protects)
#define R0_ 0
#define Q_  6656
#define P_  6656
#define VB_ 13312
#define WS_ 6656

__global__ __launch_bounds__(256, 4) void swin_mfma(
    const float* __restrict__ x,
    const float* __restrict__ ln_w, const float* __restrict__ ln_b,
    const float* __restrict__ b1,   const float* __restrict__ b2,
    const short* __restrict__ ws,
    float* __restrict__ out)
{
    __shared__ __align__(16) short lds[19456];
    const short* wsQKV = ws;
    const short* wsW1  = ws + 27648;
    const short* wsW2  = ws + 64512;

    const int tid = threadIdx.x;
    const int w = tid >> 6, lane = tid & 63, q = lane >> 4, n16 = lane & 15;
    const int win = blockIdx.x;
    const int bb = win >> 10, wh = (win >> 5) & 31, ww = win & 31;
    const int rowb = w * 16 + q * 4;          // C/D-layout row base

    // ---------- Phase A: load x, LayerNorm, bf16 -> XA (R0) ----------
    {
        int r = w * 16 + n16;
        float v[24];
        if (r < 49) {
            int i = r / 7, jj = r - i * 7;
            const float* xp = x + ((size_t)((bb * 224 + wh * 7 + i) * 224 + ww * 7 + jj)) * 96 + q * 8;
            #pragma unroll
            for (int kc = 0; kc < 3; ++kc) {
                float4 u0 = *(const float4*)(xp + kc * 32);
                float4 u1 = *(const float4*)(xp + kc * 32 + 4);
                v[kc*8+0] = u0.x; v[kc*8+1] = u0.y; v[kc*8+2] = u0.z; v[kc*8+3] = u0.w;
                v[kc*8+4] = u1.x; v[kc*8+5] = u1.y; v[kc*8+6] = u1.z; v[kc*8+7] = u1.w;
            }
        } else {
            #pragma unroll
            for (int c = 0; c < 24; ++c) v[c] = 0.f;
        }
        float s = 0.f, ss = 0.f;
        #pragma unroll
        for (int c = 0; c < 24; ++c) { s += v[c]; ss += v[c] * v[c]; }
        s  += __shfl_xor(s, 16);  s  += __shfl_xor(s, 32);
        ss += __shfl_xor(ss, 16); ss += __shfl_xor(ss, 32);
        float mean = s * (1.f / 96.f);
        float var  = ss * (1.f / 96.f) - mean * mean;
        float rstd = rsqrtf(var + 1e-5f);
        #pragma unroll
        for (int kc = 0; kc < 3; ++kc) {
            short8 o;
            #pragma unroll
            for (int j = 0; j < 8; ++j) {
                int c = kc * 32 + q * 8 + j;
                float xn = (r < 49) ? ((v[kc*8+j] - mean) * rstd * ln_w[c] + ln_b[c]) : 0.f;
                o[j] = f2bf(xn);
            }
            *(short8*)&lds[R0_ + r * 104 + kc * 32 + q * 8] = o;
        }
    }
    __syncthreads();   // XA complete (read cross-wave by af loads)

    // ---------- Phase B: QKV, N-split across waves (weights fetched once/window) ----------
    {
        short8 af[4][3];
        #pragma unroll
        for (int M = 0; M < 4; ++M)
            #pragma unroll
            for (int kc = 0; kc < 3; ++kc)
                af[M][kc] = *(const short8*)&lds[R0_ + (M * 16 + n16) * 104 + kc * 32 + q * 8];
        __syncthreads();   // all af loads done -> R0 free: K may overwrite XA

        for (int n = w; n < 18; n += 4) {
            float4v c[4];
            #pragma unroll
            for (int M = 0; M < 4; ++M) c[M] = (float4v){0.f, 0.f, 0.f, 0.f};
            #pragma unroll
            for (int kc = 0; kc < 3; ++kc) {
                short8 bf = *(const short8*)(wsQKV + ((n * 3 + kc) * 64 + lane) * 8);
                #pragma unroll
                for (int M = 0; M < 4; ++M)
                    c[M] = __builtin_amdgcn_mfma_f32_16x16x32_bf16(af[M][kc], bf, c[M], 0, 0, 0);
            }
            if (n < 12) {
                int base = (n < 6 ? Q_ + n * 16 : R0_ + (n - 6) * 16) + n16;
                #pragma unroll
                for (int M = 0; M < 4; ++M)
                    #pragma unroll
                    for (int rg = 0; rg < 4; ++rg)
                        lds[base + (M * 16 + q * 4 + rg) * 104] = f2bf(c[M][rg]);
            } else {
                int tV = n - 12;
                #pragma unroll
                for (int M = 0; M < 4; ++M)
                    #pragma unroll
                    for (int rg = 0; rg < 4; ++rg) {
                        int row = M * 16 + q * 4 + rg;
                        lds[VB_ + (((tV * 2 + (row >> 5)) * 64 + ((row >> 3) & 3) * 16 + n16) << 3) + (row & 7)]
                            = f2bf(c[M][rg]);
                    }
            }
        }
    }
    __syncthreads();   // Q (R1) / K (R0) / VB complete

    // ---------- Phase C: S = Q K^T / sqrt(96), softmax -> P (stride 72, over dead Q) ----------
    {
        short8 qf[3];
        #pragma unroll
        for (int kc = 0; kc < 3; ++kc)
            qf[kc] = *(const short8*)&lds[Q_ + (w * 16 + n16) * 104 + kc * 32 + q * 8];
        float4v sv[4];
        #pragma unroll
        for (int tn = 0; tn < 4; ++tn) sv[tn] = (float4v){0.f, 0.f, 0.f, 0.f};
        #pragma unroll
        for (int kc = 0; kc < 3; ++kc)
            #pragma unroll
            for (int tn = 0; tn < 4; ++tn) {
                short8 kf = *(const short8*)&lds[R0_ + (tn * 16 + n16) * 104 + kc * 32 + q * 8];
                sv[tn] = __builtin_amdgcn_mfma_f32_16x16x32_bf16(qf[kc], kf, sv[tn], 0, 0, 0);
            }
        __syncthreads();   // all Q/K reads done -> R0 free for O, Q region free for P
        const float rs = 0.10206207261596575f;
        #pragma unroll
        for (int rg = 0; rg < 4; ++rg) {
            float v0 = sv[0][rg] * rs;
            float v1 = sv[1][rg] * rs;
            float v2 = sv[2][rg] * rs;
            float v3 = (n16 == 0) ? sv[3][rg] * rs : -1e30f;
            float mx = fmaxf(fmaxf(v0, v1), fmaxf(v2, v3));
            #pragma unroll
            for (int o = 1; o < 16; o <<= 1) mx = fmaxf(mx, __shfl_xor(mx, o));
            float e0 = __expf(v0 - mx), e1 = __expf(v1 - mx);
            float e2 = __expf(v2 - mx), e3 = __expf(v3 - mx);
            float sum = e0 + e1 + e2 + e3;
            #pragma unroll
            for (int o = 1; o < 16; o <<= 1) sum += __shfl_xor(sum, o);
            float inv = __builtin_amdgcn_rcpf(sum);
            int pr = P_ + (rowb + rg) * 72 + n16;
            lds[pr +  0] = f2bf(e0 * inv);
            lds[pr + 16] = f2bf(e1 * inv);
            lds[pr + 32] = f2bf(e2 * inv);
            lds[pr + 48] = f2bf(e3 * inv);
        }
    }

    // ---------- Phase D: O = P @ V (own rows; bf16 O over dead K in R0; fp32 O in regs) ----------
    // P write->read and O write->read are same-wave, same-rows: in-order DS, no barrier.
    float4v ov[6];
    {
        short8 pf0 = *(const short8*)&lds[P_ + (w * 16 + n16) * 72 + q * 8];
        short8 pf1 = *(const short8*)&lds[P_ + (w * 16 + n16) * 72 + 32 + q * 8];
        #pragma unroll
        for (int tV = 0; tV < 6; ++tV) {
            float4v a = {0.f, 0.f, 0.f, 0.f};
            short8 vf0 = *(const short8*)&lds[VB_ + ((tV * 2 + 0) * 64 + lane) * 8];
            short8 vf1 = *(const short8*)&lds[VB_ + ((tV * 2 + 1) * 64 + lane) * 8];
            a = __builtin_amdgcn_mfma_f32_16x16x32_bf16(pf0, vf0, a, 0, 0, 0);
            a = __builtin_amdgcn_mfma_f32_16x16x32_bf16(pf1, vf1, a, 0, 0, 0);
            ov[tV] = a;
            #pragma unroll
            for (int rg = 0; rg < 4; ++rg)
                lds[R0_ + (rowb + rg) * 104 + tV * 16 + n16] = f2bf(a[rg]);
        }
    }

    // ---------- Phase E: MLP, W1/W2 t-slices staged into WS (over dead P+VB) ----------
    float4v y[6];
    #pragma unroll
    for (int tn = 0; tn < 6; ++tn) y[tn] = (float4v){0.f, 0.f, 0.f, 0.f};
    {
        short8 of[3];
        #pragma unroll
        for (int kc = 0; kc < 3; ++kc)
            of[kc] = *(const short8*)&lds[R0_ + (w * 16 + n16) * 104 + kc * 32 + q * 8];

        for (int t = 0; t < 4; ++t) {
            __syncthreads();                         // WS region free (D reads done / prev W2 reads done)
            {
                const short* src = wsW1 + t * 9216;
                #pragma unroll
                for (int it = 0; it < 5; ++it) {
                    int cc = tid + it * 256;
                    if (cc < 1152) stage16(src + cc * 8, &lds[WS_ + cc * 8]);
                }
            }
            __syncthreads();                         // W1_t staged
            #pragma unroll
            for (int tn = 0; tn < 6; ++tn) {
                float4v h = {0.f, 0.f, 0.f, 0.f};
                #pragma unroll
                for (int kc = 0; kc < 3; ++kc) {
                    short8 wf = *(const short8*)&lds[WS_ + ((tn * 3 + kc) * 64 + lane) * 8];
                    h = __builtin_amdgcn_mfma_f32_16x16x32_bf16(of[kc], wf, h, 0, 0, 0);
                }
                float bb1 = b1[t * 96 + tn * 16 + n16];
                #pragma unroll
                for (int rg = 0; rg < 4; ++rg)
                    lds[R0_ + (rowb + rg) * 104 + tn * 16 + n16] = f2bf(gelu_sig(h[rg] + bb1));
            }
            short8 hf[3];
            #pragma unroll
            for (int kc = 0; kc < 3; ++kc)           // same-wave H readback (in-order DS)
                hf[kc] = *(const short8*)&lds[R0_ + (w * 16 + n16) * 104 + kc * 32 + q * 8];
            __syncthreads();                         // all W1 reads done
            {
                const short* src = wsW2 + t * 9216;
                #pragma unroll
                for (int it = 0; it < 5; ++it) {
                    int cc = tid + it * 256;
                    if (cc < 1152) stage16(src + cc * 8, &lds[WS_ + cc * 8]);
                }
            }
            __syncthreads();                         // W2_t staged
            #pragma unroll
            for (int tn = 0; tn < 6; ++tn)
                #pragma unroll
                for (int kc = 0; kc < 3; ++kc) {
                    short8 wf = *(const short8*)&lds[WS_ + ((tn * 3 + kc) * 64 + lane) * 8];
                    y[tn] = __builtin_amdgcn_mfma_f32_16x16x32_bf16(hf[kc], wf, y[tn], 0, 0, 0);
                }
        }
    }

    // ---------- Epilogue: out = y + b2 + O ----------
    float b2v[6];
    #pragma unroll
    for (int tn = 0; tn < 6; ++tn) b2v[tn] = b2[tn * 16 + n16];
    #pragma unroll
    for (int rg = 0; rg < 4; ++rg) {
        int r = rowb + rg;
        if (r < 49) {
            int i = r / 7, jj = r - i * 7;
            float* op = out + ((size_t)((bb * 224 + wh * 7 + i) * 224 + ww * 7 + jj)) * 96 + n16;
            #pragma unroll
            for (int tn = 0; tn < 6; ++tn)
                op[tn * 16] = y[tn][rg] + b2v[tn] + ov[tn][rg];
        }
    }
}

extern "C" void kernel_launch(void* const* d_in, const int* in_sizes, int n_in,
                              void* d_out, int out_size, void* d_ws, size_t ws_size,
                              hipStream_t stream) {
    const float* x     = (const float*)d_in[0];
    const float* qkv_w = (const float*)d_in[1];
    const float* ln_w  = (const float*)d_in[2];
    const float* ln_b  = (const float*)d_in[3];
    const float* w1    = (const float*)d_in[4];
    const float* b1    = (const float*)d_in[5];
    const float* w2    = (const float*)d_in[6];
    const float* b2    = (const float*)d_in[7];
    float* out = (float*)d_out;
    short* ws = (short*)d_ws;

    convert_weights<<<396, 256, 0, stream>>>(qkv_w, w1, w2, ws);
    swin_mfma<<<8192, 256, 0, stream>>>(x, ln_w, ln_b, b1, b2, ws, out);
}